// Round 14
// baseline (194.179 us; speedup 1.0000x reference)
//
#include <hip/hip_runtime.h>
#include <hip/hip_bf16.h>
#include <stdint.h>

typedef __attribute__((ext_vector_type(4))) float f32x4;
typedef __attribute__((ext_vector_type(16))) float f32x16;
typedef __attribute__((ext_vector_type(8))) short s16x8;
typedef __attribute__((ext_vector_type(4))) short s16x4;
typedef __attribute__((ext_vector_type(4))) unsigned int u32x4;

#define DEV static __device__ __forceinline__

constexpr int B_ = 4, H_ = 16, N_ = 2048;
constexpr float CL_ = 0.18033688011112042f;  // dh^-0.5 * log2(e), folded into q

DEV short f2bf(float x) {
  __hip_bfloat16 h = __float2bfloat16(x);
  return *reinterpret_cast<short*>(&h);
}

DEV uint32_t cvtpk(float lo, float hi) {  // packed bf16 (RNE), 1 instr
  uint32_t r;
  asm("v_cvt_pk_bf16_f32 %0, %1, %2" : "=v"(r) : "v"(lo), "v"(hi));
  return r;
}

DEV void gload16(const void* g, void* l) {
  __builtin_amdgcn_global_load_lds((const __attribute__((address_space(1))) void*)g,
                                   (__attribute__((address_space(3))) void*)l, 16, 0, 0);
}

// ---------------- fused prep: x cast + both weight transposes (one launch) ----------
__global__ void k_prep(const float* __restrict__ x, short* __restrict__ xb,
                       const float* __restrict__ wqkv, short* __restrict__ wqkvT,
                       const float* __restrict__ wout, short* __restrict__ woutT) {
  __shared__ short t[64][72];
  int bid = blockIdx.x, tid = threadIdx.x;
  if (bid < 4096) {
    int i = (bid * 256 + tid) * 8;
    const float4* p = reinterpret_cast<const float4*>(x + i);
    float4 a = p[0], b = p[1];
    s16x8 o;
    o[0] = f2bf(a.x); o[1] = f2bf(a.y); o[2] = f2bf(a.z); o[3] = f2bf(a.w);
    o[4] = f2bf(b.x); o[5] = f2bf(b.y); o[6] = f2bf(b.z); o[7] = f2bf(b.w);
    *reinterpret_cast<s16x8*>(xb + i) = o;
    return;
  }
  const float* W;
  short* WT;
  int R = 1024, C, r0, c0;
  if (bid < 4864) {
    int id = bid - 4096;
    W = wqkv; WT = wqkvT; C = 3072;
    c0 = (id % 48) * 64; r0 = (id / 48) * 64;
  } else {
    int id = bid - 4864;
    W = wout; WT = woutT; C = 1024;
    c0 = (id % 16) * 64; r0 = (id / 16) * 64;
  }
  int r = tid >> 2, cp = (tid & 3) * 16;
  const float4* s4 = reinterpret_cast<const float4*>(W + (size_t)(r0 + r) * C + c0 + cp);
  float4 f0 = s4[0], f1 = s4[1], f2 = s4[2], f3 = s4[3];
  short* tr = &t[r][cp];
  tr[0] = f2bf(f0.x); tr[1] = f2bf(f0.y); tr[2]  = f2bf(f0.z); tr[3]  = f2bf(f0.w);
  tr[4] = f2bf(f1.x); tr[5] = f2bf(f1.y); tr[6]  = f2bf(f1.z); tr[7]  = f2bf(f1.w);
  tr[8] = f2bf(f2.x); tr[9] = f2bf(f2.y); tr[10] = f2bf(f2.z); tr[11] = f2bf(f2.w);
  tr[12] = f2bf(f3.x); tr[13] = f2bf(f3.y); tr[14] = f2bf(f3.z); tr[15] = f2bf(f3.w);
  __syncthreads();
  int cc = tid >> 2, rp = (tid & 3) * 16;
  short buf[16];
#pragma unroll
  for (int i = 0; i < 16; ++i) buf[i] = t[rp + i][cc];
  short* dst = WT + (size_t)(c0 + cc) * R + r0 + rp;
  *reinterpret_cast<s16x8*>(dst) = *reinterpret_cast<s16x8*>(buf);
  *reinterpret_cast<s16x8*>(dst + 8) = *reinterpret_cast<s16x8*>(buf + 8);
}

// ------------- GEMM0: xb[8192][1024] x wqkvT[3072][1024] -> q,k ([B][H][N][64]) + vT ----
// 128x128 tile, BK=32, 4 waves, 2-slot LDS (32KB), LB(256,2) (R11/R13 measured-best).
// 2-phase pipeline: {STAGE(t+1); ds_read(t); MFMA; vmcnt(0); barrier}.
// q pre-scaled by CL_; v written transposed to vT[B][H][64][N].
__global__ __launch_bounds__(256, 2)
void k_gemm0(const short* __restrict__ A, const short* __restrict__ BT,
             short* __restrict__ oq, short* __restrict__ ok, short* __restrict__ ovT) {
  __shared__ __align__(16) char smem[32768];  // 2 slots x (A 8KB + B 8KB)
  constexpr int K = 1024, NT = 32;
  const int tid = threadIdx.x;
  const int m0 = blockIdx.x * 128, n0 = blockIdx.y * 128;
  const int lane = tid & 63, w = tid >> 6, g = lane >> 4, c = lane & 15;
  const int wr = w >> 1, wc = w & 1;
  f32x4 acc[4][4] = {};
  const int trow = tid >> 2, tk = (tid & 3) * 8;
  const short* ga = A + (size_t)(m0 + trow) * K + tk;
  const short* gb = BT + (size_t)(n0 + trow) * K + tk;
#define STG0(T)                                                    \
  {                                                                \
    char* nb = smem + ((T) & 1) * 16384;                           \
    gload16(ga + (T) * 32, nb + tid * 16);                         \
    gload16(ga + (size_t)64 * K + (T) * 32, nb + 4096 + tid * 16); \
    gload16(gb + (T) * 32, nb + 8192 + tid * 16);                  \
    gload16(gb + (size_t)64 * K + (T) * 32, nb + 12288 + tid * 16);\
  }
  STG0(0);
  asm volatile("s_waitcnt vmcnt(0)" ::: "memory");
  __builtin_amdgcn_s_barrier();
  for (int t = 0; t < NT; ++t) {
    if (t + 1 < NT) STG0(t + 1);
    const char* sb = smem + (t & 1) * 16384;
    s16x8 af[4], bf[4];
#pragma unroll
    for (int i = 0; i < 4; ++i)
      af[i] = *reinterpret_cast<const s16x8*>(sb + (wr * 64 + i * 16 + c) * 64 + g * 16);
#pragma unroll
    for (int j = 0; j < 4; ++j)
      bf[j] = *reinterpret_cast<const s16x8*>(sb + 8192 + (wc * 64 + j * 16 + c) * 64 + g * 16);
    __builtin_amdgcn_s_setprio(1);
#pragma unroll
    for (int i = 0; i < 4; ++i)
#pragma unroll
      for (int j = 0; j < 4; ++j)
        acc[i][j] = __builtin_amdgcn_mfma_f32_16x16x32_bf16(af[i], bf[j], acc[i][j], 0, 0, 0);
    __builtin_amdgcn_s_setprio(0);
    asm volatile("s_waitcnt vmcnt(0)" ::: "memory");
    __builtin_amdgcn_s_barrier();
  }
#undef STG0
  // epilogue: part 0 -> q (scaled), 1 -> k, 2 -> vT (packed 8B rows along n)
#pragma unroll
  for (int bj = 0; bj < 4; ++bj) {
    int ncol = n0 + wc * 64 + bj * 16 + c;
    int part = ncol >> 10;
    int c10 = ncol & 1023;
    int h = c10 >> 6, d = c10 & 63;
    if (part == 2) {
#pragma unroll
      for (int ai = 0; ai < 4; ++ai) {
        int mrow = m0 + wr * 64 + ai * 16 + g * 4;  // 4 consecutive rows
        int b = mrow >> 11, nr = mrow & 2047;
        uint2 pk;
        pk.x = cvtpk(acc[ai][bj][0], acc[ai][bj][1]);
        pk.y = cvtpk(acc[ai][bj][2], acc[ai][bj][3]);
        *reinterpret_cast<uint2*>(ovT + ((size_t)((b * H_ + h) * 64 + d) * N_ + nr)) = pk;
      }
    } else {
      short* dst0 = (part == 0) ? oq : ok;
      float qs = (part == 0) ? CL_ : 1.0f;
#pragma unroll
      for (int ai = 0; ai < 4; ++ai) {
#pragma unroll
        for (int r = 0; r < 4; ++r) {
          int mrow = m0 + wr * 64 + ai * 16 + g * 4 + r;
          int b = mrow >> 11, nr = mrow & 2047;
          dst0[((size_t)((b * H_ + h) * N_ + nr) << 6) + d] = f2bf(acc[ai][bj][r] * qs);
        }
      }
    }
  }
}

// ------------- GEMM1 (out-proj): 64x128 tile (M-split), 4 blocks/CU, 2-phase loop ----
// 4 waves 2x2: wave = 32(m) x 64(n), acc[2][4] (32 VGPR). LDS 2 x (A 4KB + B 8KB).
// M-split keeps A-traffic at R11's level (8 N-tiles); B (2MB) re-read is L2-cheap.
__global__ __launch_bounds__(256, 4)
void k_gemm1(const short* __restrict__ A, const short* __restrict__ BT,
             int M, int N, int K, const float* __restrict__ bias, float* __restrict__ out) {
  __shared__ __align__(16) char smem[24576];
  const int NT = K / 32;
  const int tid = threadIdx.x;
  const int m0 = blockIdx.x * 64, n0 = blockIdx.y * 128;
  const int lane = tid & 63, w = tid >> 6, g = lane >> 4, c = lane & 15;
  const int wr = w >> 1, wc = w & 1;
  f32x4 acc[2][4] = {};
  const int trow = tid >> 2, tk = (tid & 3) * 8;  // trow 0..63
  const short* ga = A + (size_t)(m0 + trow) * K + tk;
  const short* gb0 = BT + (size_t)(n0 + trow) * K + tk;
  const short* gb1 = BT + (size_t)(n0 + 64 + trow) * K + tk;
#define STG1(T)                                                    \
  {                                                                \
    char* nb = smem + ((T) & 1) * 12288;                           \
    gload16(ga + (T) * 32, nb + tid * 16);                         \
    gload16(gb0 + (T) * 32, nb + 4096 + tid * 16);                 \
    gload16(gb1 + (T) * 32, nb + 8192 + tid * 16);                 \
  }
  STG1(0);
  asm volatile("s_waitcnt vmcnt(0)" ::: "memory");
  __builtin_amdgcn_s_barrier();
  for (int t = 0; t < NT; ++t) {
    if (t + 1 < NT) STG1(t + 1);
    const char* sb = smem + (t & 1) * 12288;
    s16x8 af[2], bf[4];
#pragma unroll
    for (int i = 0; i < 2; ++i)
      af[i] = *reinterpret_cast<const s16x8*>(sb + (wr * 32 + i * 16 + c) * 64 + g * 16);
#pragma unroll
    for (int j = 0; j < 4; ++j)
      bf[j] = *reinterpret_cast<const s16x8*>(sb + 4096 + (wc * 64 + j * 16 + c) * 64 + g * 16);
    __builtin_amdgcn_s_setprio(1);
#pragma unroll
    for (int i = 0; i < 2; ++i)
#pragma unroll
      for (int j = 0; j < 4; ++j)
        acc[i][j] = __builtin_amdgcn_mfma_f32_16x16x32_bf16(af[i], bf[j], acc[i][j], 0, 0, 0);
    __builtin_amdgcn_s_setprio(0);
    asm volatile("s_waitcnt vmcnt(0)" ::: "memory");
    __builtin_amdgcn_s_barrier();
  }
#undef STG1
#pragma unroll
  for (int bj = 0; bj < 4; ++bj) {
    int ncol = n0 + wc * 64 + bj * 16 + c;
    float bb = bias[ncol];
#pragma unroll
    for (int ai = 0; ai < 2; ++ai) {
#pragma unroll
      for (int r = 0; r < 4; ++r) {
        int mrow = m0 + wr * 32 + ai * 16 + g * 4 + r;
        out[(size_t)mrow * N + ncol] = acc[ai][bj][r] + bb;
      }
    }
  }
}

// ------------- flash attention: 32x32 MFMA, QBLK=32/wave, 4 blocks/CU (unchanged) ------
__global__ __launch_bounds__(256, 4)
void k_attn(const short* __restrict__ q, const short* __restrict__ kk,
            const short* __restrict__ vT, short* __restrict__ ao) {
  __shared__ __align__(16) char smem[32768];  // 2 slots x (K 8K + V 8K)
  constexpr int NT = N_ / 64;  // 32 kv tiles
  int bh = blockIdx.x, qb = blockIdx.y;  // bh fast => same-head blocks on one XCD
  int b = bh >> 4, head = bh & 15;
  int tid = threadIdx.x, w = tid >> 6, lane = tid & 63;
  int half = lane >> 5, qc = lane & 31;
  const size_t ho = (size_t)bh * (N_ * 64);
  const short* Q = q + ho;
  const char* Kc = reinterpret_cast<const char*>(kk + ho);
  const char* Vc = reinterpret_cast<const char*>(vT + ho);
  int q0w = qb * 128 + w * 32;
  s16x8 qf[4];
#pragma unroll
  for (int ks = 0; ks < 4; ++ks)
    qf[ks] = *reinterpret_cast<const s16x8*>(Q + (size_t)(q0w + qc) * 64 + ks * 16 + half * 8);
  f32x16 ot[2] = {};
  float lp0 = 0.f, lp1 = 0.f, lp2 = 0.f, lp3 = 0.f;
  const int rsw0 = ((qc ^ (qc >> 3)) & 7) << 4;
  const int rsw1 = rsw0 ^ 0x40;
  const int s_i0 = tid, s_i1 = tid + 256;
  const int s_r0 = s_i0 >> 3, s_r1 = s_i1 >> 3;
  const int s_c0 = (((s_i0 & 7) ^ ((s_r0 ^ (s_r0 >> 3)) & 7)) << 4);
  const int s_c1 = (((s_i1 & 7) ^ ((s_r1 ^ (s_r1 >> 3)) & 7)) << 4);
#define STAGE(T)                                                                       \
  {                                                                                    \
    char* nb = smem + ((T) & 1) * 16384;                                               \
    gload16(Kc + (size_t)((T) * 64 + s_r0) * 128 + s_c0, nb + s_i0 * 16);              \
    gload16(Kc + (size_t)((T) * 64 + s_r1) * 128 + s_c1, nb + s_i1 * 16);              \
    gload16(Vc + (size_t)s_r0 * 4096 + (T) * 128 + s_c0, nb + 8192 + s_i0 * 16);       \
    gload16(Vc + (size_t)s_r1 * 4096 + (T) * 128 + s_c1, nb + 8192 + s_i1 * 16);       \
  }
  STAGE(0);
  __syncthreads();
  for (int tt = 0; tt < NT; ++tt) {
    if (tt + 1 < NT) STAGE(tt + 1);
    const char* kb_ = smem + (tt & 1) * 16384;
    const char* vb_ = kb_ + 8192;
    f32x16 st[2];
#pragma unroll
    for (int j = 0; j < 2; ++j) {
      const int rs = j ? rsw1 : rsw0;
      s16x8 kfj[4];
#pragma unroll
      for (int ks = 0; ks < 4; ++ks)
        kfj[ks] = *reinterpret_cast<const s16x8*>(kb_ + (j * 32 + qc) * 128 + ((ks * 32 + half * 16) ^ rs));
      f32x16 acc = {};
      __builtin_amdgcn_s_setprio(1);
#pragma unroll
      for (int ks = 0; ks < 4; ++ks)
        acc = __builtin_amdgcn_mfma_f32_32x32x16_bf16(kfj[ks], qf[ks], acc, 0, 0, 0);
      __builtin_amdgcn_s_setprio(0);
      st[j] = acc;
    }
#pragma unroll
    for (int j = 0; j < 2; ++j)
#pragma unroll
      for (int r = 0; r < 16; ++r) {
        float p = __builtin_amdgcn_exp2f(st[j][r]);
        st[j][r] = p;
        if ((r & 3) == 0) lp0 += p;
        else if ((r & 3) == 1) lp1 += p;
        else if ((r & 3) == 2) lp2 += p;
        else lp3 += p;
      }
    u32x4 pwv[4];
#pragma unroll
    for (int j = 0; j < 2; ++j)
#pragma unroll
      for (int bb = 0; bb < 2; ++bb)
#pragma unroll
        for (int p = 0; p < 2; ++p) {
          uint32_t Aw = cvtpk(st[j][8 * bb + 2 * p], st[j][8 * bb + 2 * p + 1]);
          uint32_t Bw = cvtpk(st[j][8 * bb + 4 + 2 * p], st[j][8 * bb + 4 + 2 * p + 1]);
          asm volatile("v_permlane32_swap_b32 %0, %1" : "+v"(Aw), "+v"(Bw));
          pwv[j * 2 + bb][p] = Aw;
          pwv[j * 2 + bb][p + 2] = Bw;
        }
#pragma unroll
    for (int db = 0; db < 2; ++db) {
      const int rs = db ? rsw1 : rsw0;
      s16x8 vf[4];
#pragma unroll
      for (int kb4 = 0; kb4 < 4; ++kb4)
        vf[kb4] = *reinterpret_cast<const s16x8*>(vb_ + (db * 32 + qc) * 128 + ((kb4 * 32 + half * 16) ^ rs));
      f32x16 acc = ot[db];
      __builtin_amdgcn_s_setprio(1);
#pragma unroll
      for (int kb4 = 0; kb4 < 4; ++kb4)
        acc = __builtin_amdgcn_mfma_f32_32x32x16_bf16(
            vf[kb4], __builtin_bit_cast(s16x8, pwv[kb4]), acc, 0, 0, 0);
      __builtin_amdgcn_s_setprio(0);
      ot[db] = acc;
    }
    __syncthreads();
  }
#undef STAGE
  float lp = (lp0 + lp1) + (lp2 + lp3);
  float linv = 1.f / (lp + __shfl_xor(lp, 32, 64));
  short* Oq = reinterpret_cast<short*>(smem) + w * 2304;  // [32][72]
#pragma unroll
  for (int db = 0; db < 2; ++db)
#pragma unroll
    for (int m = 0; m < 4; ++m) {
      uint2 pk;
      pk.x = cvtpk(ot[db][4 * m] * linv, ot[db][4 * m + 1] * linv);
      pk.y = cvtpk(ot[db][4 * m + 2] * linv, ot[db][4 * m + 3] * linv);
      *reinterpret_cast<uint2*>(Oq + qc * 72 + db * 32 + m * 8 + half * 4) = pk;
    }
  int q2 = lane >> 1, dcol = (lane & 1) * 32;
  size_t ro = (size_t)(b * N_ + q0w + q2) * 1024 + head * 64 + dcol;
#pragma unroll
  for (int ch = 0; ch < 4; ++ch) {
    s16x8 vv = *reinterpret_cast<const s16x8*>(Oq + q2 * 72 + dcol + ch * 8);
    *reinterpret_cast<s16x8*>(ao + ro + ch * 8) = vv;
  }
}

extern "C" void kernel_launch(void* const* d_in, const int* in_sizes, int n_in,
                              void* d_out, int out_size, void* d_ws, size_t ws_size,
                              hipStream_t stream) {
  const float* x = (const float*)d_in[0];
  const float* w_qkv = (const float*)d_in[1];
  const float* w_out = (const float*)d_in[2];
  const float* b_out = (const float*)d_in[3];
  float* out = (float*)d_out;
  char* ws = (char*)d_ws;
  short* xb    = (short*)(ws);                // [8192][1024] bf16 (reused as ao later)
  short* wqkvT = (short*)(ws + 16777216);     // [3072][1024]
  short* woutT = (short*)(ws + 23068672);     // [1024][1024]
  short* qB    = (short*)(ws + 25165824);     // [B][H][N][64] (pre-scaled by CL_)
  short* kB    = (short*)(ws + 41943040);
  short* vTT   = (short*)(ws + 75497472);     // [B][H][64][N] (written by gemm0)
  short* ao    = xb;                          // alias: xb dead after gemm0

  k_prep<<<5120, 256, 0, stream>>>(x, xb, w_qkv, wqkvT, w_out, woutT);
  k_gemm0<<<dim3(64, 24), 256, 0, stream>>>(xb, wqkvT, qB, kB, vTT);
  k_attn<<<dim3(64, 16), 256, 0, stream>>>(qB, kB, vTT, ao);
  k_gemm1<<<dim3(128, 8), 256, 0, stream>>>(ao, woutT, 8192, 1024, 1024, b_out, out);
}

// Round 16
// 188.255 us; speedup vs baseline: 1.0315x; 1.0315x over previous
//
#include <hip/hip_runtime.h>
#include <hip/hip_bf16.h>
#include <stdint.h>

typedef __attribute__((ext_vector_type(4))) float f32x4;
typedef __attribute__((ext_vector_type(16))) float f32x16;
typedef __attribute__((ext_vector_type(8))) short s16x8;
typedef __attribute__((ext_vector_type(4))) short s16x4;
typedef __attribute__((ext_vector_type(4))) unsigned int u32x4;

#define DEV static __device__ __forceinline__

constexpr int B_ = 4, H_ = 16, N_ = 2048;
constexpr float CL_ = 0.18033688011112042f;  // dh^-0.5 * log2(e), folded into q

DEV short f2bf(float x) {
  __hip_bfloat16 h = __float2bfloat16(x);
  return *reinterpret_cast<short*>(&h);
}

DEV uint32_t cvtpk(float lo, float hi) {  // packed bf16 (RNE), 1 instr
  uint32_t r;
  asm("v_cvt_pk_bf16_f32 %0, %1, %2" : "=v"(r) : "v"(lo), "v"(hi));
  return r;
}

DEV void gload16(const void* g, void* l) {
  __builtin_amdgcn_global_load_lds((const __attribute__((address_space(1))) void*)g,
                                   (__attribute__((address_space(3))) void*)l, 16, 0, 0);
}

// ---------------- fused prep: x cast + both weight transposes (one launch) ----------
__global__ void k_prep(const float* __restrict__ x, short* __restrict__ xb,
                       const float* __restrict__ wqkv, short* __restrict__ wqkvT,
                       const float* __restrict__ wout, short* __restrict__ woutT) {
  __shared__ short t[64][72];
  int bid = blockIdx.x, tid = threadIdx.x;
  if (bid < 4096) {
    int i = (bid * 256 + tid) * 8;
    const float4* p = reinterpret_cast<const float4*>(x + i);
    float4 a = p[0], b = p[1];
    s16x8 o;
    o[0] = f2bf(a.x); o[1] = f2bf(a.y); o[2] = f2bf(a.z); o[3] = f2bf(a.w);
    o[4] = f2bf(b.x); o[5] = f2bf(b.y); o[6] = f2bf(b.z); o[7] = f2bf(b.w);
    *reinterpret_cast<s16x8*>(xb + i) = o;
    return;
  }
  const float* W;
  short* WT;
  int R = 1024, C, r0, c0;
  if (bid < 4864) {
    int id = bid - 4096;
    W = wqkv; WT = wqkvT; C = 3072;
    c0 = (id % 48) * 64; r0 = (id / 48) * 64;
  } else {
    int id = bid - 4864;
    W = wout; WT = woutT; C = 1024;
    c0 = (id % 16) * 64; r0 = (id / 16) * 64;
  }
  int r = tid >> 2, cp = (tid & 3) * 16;
  const float4* s4 = reinterpret_cast<const float4*>(W + (size_t)(r0 + r) * C + c0 + cp);
  float4 f0 = s4[0], f1 = s4[1], f2 = s4[2], f3 = s4[3];
  short* tr = &t[r][cp];
  tr[0] = f2bf(f0.x); tr[1] = f2bf(f0.y); tr[2]  = f2bf(f0.z); tr[3]  = f2bf(f0.w);
  tr[4] = f2bf(f1.x); tr[5] = f2bf(f1.y); tr[6]  = f2bf(f1.z); tr[7]  = f2bf(f1.w);
  tr[8] = f2bf(f2.x); tr[9] = f2bf(f2.y); tr[10] = f2bf(f2.z); tr[11] = f2bf(f2.w);
  tr[12] = f2bf(f3.x); tr[13] = f2bf(f3.y); tr[14] = f2bf(f3.z); tr[15] = f2bf(f3.w);
  __syncthreads();
  int cc = tid >> 2, rp = (tid & 3) * 16;
  short buf[16];
#pragma unroll
  for (int i = 0; i < 16; ++i) buf[i] = t[rp + i][cc];
  short* dst = WT + (size_t)(c0 + cc) * R + r0 + rp;
  *reinterpret_cast<s16x8*>(dst) = *reinterpret_cast<s16x8*>(buf);
  *reinterpret_cast<s16x8*>(dst + 8) = *reinterpret_cast<s16x8*>(buf + 8);
}

// ------------- GEMM0: xb[8192][1024] x wqkvT[3072][1024] -> q,k ([B][H][N][64]) + vT ----
// 128x128 tile, BK=32, 4 waves, 2-slot LDS (32KB), LB(256,2). 2-phase pipeline:
// per tile {STAGE(t+1); ds_read(t); MFMA; vmcnt(0); barrier}.
// q pre-scaled by CL_; v written transposed to vT[B][H][64][N].
__global__ __launch_bounds__(256, 2)
void k_gemm0(const short* __restrict__ A, const short* __restrict__ BT,
             short* __restrict__ oq, short* __restrict__ ok, short* __restrict__ ovT) {
  __shared__ __align__(16) char smem[32768];  // 2 slots x (A 8KB + B 8KB)
  constexpr int K = 1024, NT = 32;
  const int tid = threadIdx.x;
  const int m0 = blockIdx.x * 128, n0 = blockIdx.y * 128;
  const int lane = tid & 63, w = tid >> 6, g = lane >> 4, c = lane & 15;
  const int wr = w >> 1, wc = w & 1;
  f32x4 acc[4][4] = {};
  const int trow = tid >> 2, tk = (tid & 3) * 8;
  const short* ga = A + (size_t)(m0 + trow) * K + tk;
  const short* gb = BT + (size_t)(n0 + trow) * K + tk;
#define STG0(T)                                                    \
  {                                                                \
    char* nb = smem + ((T) & 1) * 16384;                           \
    gload16(ga + (T) * 32, nb + tid * 16);                         \
    gload16(ga + (size_t)64 * K + (T) * 32, nb + 4096 + tid * 16); \
    gload16(gb + (T) * 32, nb + 8192 + tid * 16);                  \
    gload16(gb + (size_t)64 * K + (T) * 32, nb + 12288 + tid * 16);\
  }
  STG0(0);
  asm volatile("s_waitcnt vmcnt(0)" ::: "memory");
  __builtin_amdgcn_s_barrier();
  for (int t = 0; t < NT; ++t) {
    if (t + 1 < NT) STG0(t + 1);
    const char* sb = smem + (t & 1) * 16384;
    s16x8 af[4], bf[4];
#pragma unroll
    for (int i = 0; i < 4; ++i)
      af[i] = *reinterpret_cast<const s16x8*>(sb + (wr * 64 + i * 16 + c) * 64 + g * 16);
#pragma unroll
    for (int j = 0; j < 4; ++j)
      bf[j] = *reinterpret_cast<const s16x8*>(sb + 8192 + (wc * 64 + j * 16 + c) * 64 + g * 16);
    __builtin_amdgcn_s_setprio(1);
#pragma unroll
    for (int i = 0; i < 4; ++i)
#pragma unroll
      for (int j = 0; j < 4; ++j)
        acc[i][j] = __builtin_amdgcn_mfma_f32_16x16x32_bf16(af[i], bf[j], acc[i][j], 0, 0, 0);
    __builtin_amdgcn_s_setprio(0);
    asm volatile("s_waitcnt vmcnt(0)" ::: "memory");
    __builtin_amdgcn_s_barrier();
  }
#undef STG0
  // epilogue: part 0 -> q (scaled), 1 -> k, 2 -> vT (packed 8B rows along n)
#pragma unroll
  for (int bj = 0; bj < 4; ++bj) {
    int ncol = n0 + wc * 64 + bj * 16 + c;
    int part = ncol >> 10;
    int c10 = ncol & 1023;
    int h = c10 >> 6, d = c10 & 63;
    if (part == 2) {
#pragma unroll
      for (int ai = 0; ai < 4; ++ai) {
        int mrow = m0 + wr * 64 + ai * 16 + g * 4;  // 4 consecutive rows
        int b = mrow >> 11, nr = mrow & 2047;
        uint2 pk;
        pk.x = cvtpk(acc[ai][bj][0], acc[ai][bj][1]);
        pk.y = cvtpk(acc[ai][bj][2], acc[ai][bj][3]);
        *reinterpret_cast<uint2*>(ovT + ((size_t)((b * H_ + h) * 64 + d) * N_ + nr)) = pk;
      }
    } else {
      short* dst0 = (part == 0) ? oq : ok;
      float qs = (part == 0) ? CL_ : 1.0f;
#pragma unroll
      for (int ai = 0; ai < 4; ++ai) {
#pragma unroll
        for (int r = 0; r < 4; ++r) {
          int mrow = m0 + wr * 64 + ai * 16 + g * 4 + r;
          int b = mrow >> 11, nr = mrow & 2047;
          dst0[((size_t)((b * H_ + h) * N_ + nr) << 6) + d] = f2bf(acc[ai][bj][r] * qs);
        }
      }
    }
  }
}

// ------------- GEMM1 (out-proj): 128x128 tile, LB(256,2), 2-phase loop ----
__global__ __launch_bounds__(256, 2)
void k_gemm1(const short* __restrict__ A, const short* __restrict__ BT,
             int M, int N, int K, const float* __restrict__ bias, float* __restrict__ out) {
  __shared__ __align__(16) char smem[32768];
  const int NT = K / 32;
  const int tid = threadIdx.x;
  const int m0 = blockIdx.x * 128, n0 = blockIdx.y * 128;
  const int lane = tid & 63, w = tid >> 6, g = lane >> 4, c = lane & 15;
  const int wr = w >> 1, wc = w & 1;
  f32x4 acc[4][4] = {};
  const int trow = tid >> 2, tk = (tid & 3) * 8;
  const short* ga = A + (size_t)(m0 + trow) * K + tk;
  const short* gb = BT + (size_t)(n0 + trow) * K + tk;
#define STG1(T)                                                    \
  {                                                                \
    char* nb = smem + ((T) & 1) * 16384;                           \
    gload16(ga + (T) * 32, nb + tid * 16);                         \
    gload16(ga + (size_t)64 * K + (T) * 32, nb + 4096 + tid * 16); \
    gload16(gb + (T) * 32, nb + 8192 + tid * 16);                  \
    gload16(gb + (size_t)64 * K + (T) * 32, nb + 12288 + tid * 16);\
  }
  STG1(0);
  asm volatile("s_waitcnt vmcnt(0)" ::: "memory");
  __builtin_amdgcn_s_barrier();
  for (int t = 0; t < NT; ++t) {
    if (t + 1 < NT) STG1(t + 1);
    const char* sb = smem + (t & 1) * 16384;
    s16x8 af[4], bf[4];
#pragma unroll
    for (int i = 0; i < 4; ++i)
      af[i] = *reinterpret_cast<const s16x8*>(sb + (wr * 64 + i * 16 + c) * 64 + g * 16);
#pragma unroll
    for (int j = 0; j < 4; ++j)
      bf[j] = *reinterpret_cast<const s16x8*>(sb + 8192 + (wc * 64 + j * 16 + c) * 64 + g * 16);
    __builtin_amdgcn_s_setprio(1);
#pragma unroll
    for (int i = 0; i < 4; ++i)
#pragma unroll
      for (int j = 0; j < 4; ++j)
        acc[i][j] = __builtin_amdgcn_mfma_f32_16x16x32_bf16(af[i], bf[j], acc[i][j], 0, 0, 0);
    __builtin_amdgcn_s_setprio(0);
    asm volatile("s_waitcnt vmcnt(0)" ::: "memory");
    __builtin_amdgcn_s_barrier();
  }
#undef STG1
#pragma unroll
  for (int bj = 0; bj < 4; ++bj) {
    int ncol = n0 + wc * 64 + bj * 16 + c;
    float bb = bias[ncol];
#pragma unroll
    for (int ai = 0; ai < 4; ++ai) {
#pragma unroll
      for (int r = 0; r < 4; ++r) {
        int mrow = m0 + wr * 64 + ai * 16 + g * 4 + r;
        out[(size_t)mrow * N + ncol] = acc[ai][bj][r] + bb;
      }
    }
  }
}

// ------------- flash attention: 32x32 MFMA, QBLK=32/wave, 4 blocks/CU (unchanged) ------
__global__ __launch_bounds__(256, 4)
void k_attn(const short* __restrict__ q, const short* __restrict__ kk,
            const short* __restrict__ vT, short* __restrict__ ao) {
  __shared__ __align__(16) char smem[32768];  // 2 slots x (K 8K + V 8K)
  constexpr int NT = N_ / 64;  // 32 kv tiles
  int bh = blockIdx.x, qb = blockIdx.y;  // bh fast => same-head blocks on one XCD
  int b = bh >> 4, head = bh & 15;
  int tid = threadIdx.x, w = tid >> 6, lane = tid & 63;
  int half = lane >> 5, qc = lane & 31;
  const size_t ho = (size_t)bh * (N_ * 64);
  const short* Q = q + ho;
  const char* Kc = reinterpret_cast<const char*>(kk + ho);
  const char* Vc = reinterpret_cast<const char*>(vT + ho);
  int q0w = qb * 128 + w * 32;
  s16x8 qf[4];
#pragma unroll
  for (int ks = 0; ks < 4; ++ks)
    qf[ks] = *reinterpret_cast<const s16x8*>(Q + (size_t)(q0w + qc) * 64 + ks * 16 + half * 8);
  f32x16 ot[2] = {};
  float lp0 = 0.f, lp1 = 0.f, lp2 = 0.f, lp3 = 0.f;
  const int rsw0 = ((qc ^ (qc >> 3)) & 7) << 4;
  const int rsw1 = rsw0 ^ 0x40;
  const int s_i0 = tid, s_i1 = tid + 256;
  const int s_r0 = s_i0 >> 3, s_r1 = s_i1 >> 3;
  const int s_c0 = (((s_i0 & 7) ^ ((s_r0 ^ (s_r0 >> 3)) & 7)) << 4);
  const int s_c1 = (((s_i1 & 7) ^ ((s_r1 ^ (s_r1 >> 3)) & 7)) << 4);
#define STAGE(T)                                                                       \
  {                                                                                    \
    char* nb = smem + ((T) & 1) * 16384;                                               \
    gload16(Kc + (size_t)((T) * 64 + s_r0) * 128 + s_c0, nb + s_i0 * 16);              \
    gload16(Kc + (size_t)((T) * 64 + s_r1) * 128 + s_c1, nb + s_i1 * 16);              \
    gload16(Vc + (size_t)s_r0 * 4096 + (T) * 128 + s_c0, nb + 8192 + s_i0 * 16);       \
    gload16(Vc + (size_t)s_r1 * 4096 + (T) * 128 + s_c1, nb + 8192 + s_i1 * 16);       \
  }
  STAGE(0);
  __syncthreads();
  for (int tt = 0; tt < NT; ++tt) {
    if (tt + 1 < NT) STAGE(tt + 1);
    const char* kb_ = smem + (tt & 1) * 16384;
    const char* vb_ = kb_ + 8192;
    f32x16 st[2];
#pragma unroll
    for (int j = 0; j < 2; ++j) {
      const int rs = j ? rsw1 : rsw0;
      s16x8 kfj[4];
#pragma unroll
      for (int ks = 0; ks < 4; ++ks)
        kfj[ks] = *reinterpret_cast<const s16x8*>(kb_ + (j * 32 + qc) * 128 + ((ks * 32 + half * 16) ^ rs));
      f32x16 acc = {};
      __builtin_amdgcn_s_setprio(1);
#pragma unroll
      for (int ks = 0; ks < 4; ++ks)
        acc = __builtin_amdgcn_mfma_f32_32x32x16_bf16(kfj[ks], qf[ks], acc, 0, 0, 0);
      __builtin_amdgcn_s_setprio(0);
      st[j] = acc;
    }
#pragma unroll
    for (int j = 0; j < 2; ++j)
#pragma unroll
      for (int r = 0; r < 16; ++r) {
        float p = __builtin_amdgcn_exp2f(st[j][r]);
        st[j][r] = p;
        if ((r & 3) == 0) lp0 += p;
        else if ((r & 3) == 1) lp1 += p;
        else if ((r & 3) == 2) lp2 += p;
        else lp3 += p;
      }
    u32x4 pwv[4];
#pragma unroll
    for (int j = 0; j < 2; ++j)
#pragma unroll
      for (int bb = 0; bb < 2; ++bb)
#pragma unroll
        for (int p = 0; p < 2; ++p) {
          uint32_t Aw = cvtpk(st[j][8 * bb + 2 * p], st[j][8 * bb + 2 * p + 1]);
          uint32_t Bw = cvtpk(st[j][8 * bb + 4 + 2 * p], st[j][8 * bb + 4 + 2 * p + 1]);
          asm volatile("v_permlane32_swap_b32 %0, %1" : "+v"(Aw), "+v"(Bw));
          pwv[j * 2 + bb][p] = Aw;
          pwv[j * 2 + bb][p + 2] = Bw;
        }
#pragma unroll
    for (int db = 0; db < 2; ++db) {
      const int rs = db ? rsw1 : rsw0;
      s16x8 vf[4];
#pragma unroll
      for (int kb4 = 0; kb4 < 4; ++kb4)
        vf[kb4] = *reinterpret_cast<const s16x8*>(vb_ + (db * 32 + qc) * 128 + ((kb4 * 32 + half * 16) ^ rs));
      f32x16 acc = ot[db];
      __builtin_amdgcn_s_setprio(1);
#pragma unroll
      for (int kb4 = 0; kb4 < 4; ++kb4)
        acc = __builtin_amdgcn_mfma_f32_32x32x16_bf16(
            vf[kb4], __builtin_bit_cast(s16x8, pwv[kb4]), acc, 0, 0, 0);
      __builtin_amdgcn_s_setprio(0);
      ot[db] = acc;
    }
    __syncthreads();
  }
#undef STAGE
  float lp = (lp0 + lp1) + (lp2 + lp3);
  float linv = 1.f / (lp + __shfl_xor(lp, 32, 64));
  short* Oq = reinterpret_cast<short*>(smem) + w * 2304;  // [32][72]
#pragma unroll
  for (int db = 0; db < 2; ++db)
#pragma unroll
    for (int m = 0; m < 4; ++m) {
      uint2 pk;
      pk.x = cvtpk(ot[db][4 * m] * linv, ot[db][4 * m + 1] * linv);
      pk.y = cvtpk(ot[db][4 * m + 2] * linv, ot[db][4 * m + 3] * linv);
      *reinterpret_cast<uint2*>(Oq + qc * 72 + db * 32 + m * 8 + half * 4) = pk;
    }
  int q2 = lane >> 1, dcol = (lane & 1) * 32;
  size_t ro = (size_t)(b * N_ + q0w + q2) * 1024 + head * 64 + dcol;
#pragma unroll
  for (int ch = 0; ch < 4; ++ch) {
    s16x8 vv = *reinterpret_cast<const s16x8*>(Oq + q2 * 72 + dcol + ch * 8);
    *reinterpret_cast<s16x8*>(ao + ro + ch * 8) = vv;
  }
}

extern "C" void kernel_launch(void* const* d_in, const int* in_sizes, int n_in,
                              void* d_out, int out_size, void* d_ws, size_t ws_size,
                              hipStream_t stream) {
  const float* x = (const float*)d_in[0];
  const float* w_qkv = (const float*)d_in[1];
  const float* w_out = (const float*)d_in[2];
  const float* b_out = (const float*)d_in[3];
  float* out = (float*)d_out;
  char* ws = (char*)d_ws;
  short* xb    = (short*)(ws);                // [8192][1024] bf16 (reused as ao later)
  short* wqkvT = (short*)(ws + 16777216);     // [3072][1024]
  short* woutT = (short*)(ws + 23068672);     // [1024][1024]
  short* qB    = (short*)(ws + 25165824);     // [B][H][N][64] (pre-scaled by CL_)
  short* kB    = (short*)(ws + 41943040);
  short* vTT   = (short*)(ws + 75497472);     // [B][H][64][N] (written by gemm0)
  short* ao    = xb;                          // alias: xb dead after gemm0

  k_prep<<<5120, 256, 0, stream>>>(x, xb, w_qkv, wqkvT, w_out, woutT);
  k_gemm0<<<dim3(64, 24), 256, 0, stream>>>(xb, wqkvT, qB, kB, vTT);
  k_attn<<<dim3(64, 16), 256, 0, stream>>>(qB, kB, vTT, ao);
  k_gemm1<<<dim3(64, 8), 256, 0, stream>>>(ao, woutT, 8192, 1024, 1024, b_out, out);
}

// Round 17
// 186.264 us; speedup vs baseline: 1.0425x; 1.0107x over previous
//
#include <hip/hip_runtime.h>
#include <hip/hip_bf16.h>
#include <stdint.h>

typedef __attribute__((ext_vector_type(4))) float f32x4;
typedef __attribute__((ext_vector_type(16))) float f32x16;
typedef __attribute__((ext_vector_type(8))) short s16x8;
typedef __attribute__((ext_vector_type(4))) short s16x4;
typedef __attribute__((ext_vector_type(4))) unsigned int u32x4;

#define DEV static __device__ __forceinline__

constexpr int B_ = 4, H_ = 16, N_ = 2048;
constexpr float CL_ = 0.18033688011112042f;  // dh^-0.5 * log2(e), folded into q

DEV short f2bf(float x) {
  __hip_bfloat16 h = __float2bfloat16(x);
  return *reinterpret_cast<short*>(&h);
}

DEV uint32_t cvtpk(float lo, float hi) {  // packed bf16 (RNE), 1 instr
  uint32_t r;
  asm("v_cvt_pk_bf16_f32 %0, %1, %2" : "=v"(r) : "v"(lo), "v"(hi));
  return r;
}

DEV void gload16(const void* g, void* l) {
  __builtin_amdgcn_global_load_lds((const __attribute__((address_space(1))) void*)g,
                                   (__attribute__((address_space(3))) void*)l, 16, 0, 0);
}

// ---------------- fused prep: x cast + both weight transposes (one launch) ----------
__global__ void k_prep(const float* __restrict__ x, short* __restrict__ xb,
                       const float* __restrict__ wqkv, short* __restrict__ wqkvT,
                       const float* __restrict__ wout, short* __restrict__ woutT) {
  __shared__ short t[64][72];
  int bid = blockIdx.x, tid = threadIdx.x;
  if (bid < 4096) {
    int i = (bid * 256 + tid) * 8;
    const float4* p = reinterpret_cast<const float4*>(x + i);
    float4 a = p[0], b = p[1];
    s16x8 o;
    o[0] = f2bf(a.x); o[1] = f2bf(a.y); o[2] = f2bf(a.z); o[3] = f2bf(a.w);
    o[4] = f2bf(b.x); o[5] = f2bf(b.y); o[6] = f2bf(b.z); o[7] = f2bf(b.w);
    *reinterpret_cast<s16x8*>(xb + i) = o;
    return;
  }
  const float* W;
  short* WT;
  int R = 1024, C, r0, c0;
  if (bid < 4864) {
    int id = bid - 4096;
    W = wqkv; WT = wqkvT; C = 3072;
    c0 = (id % 48) * 64; r0 = (id / 48) * 64;
  } else {
    int id = bid - 4864;
    W = wout; WT = woutT; C = 1024;
    c0 = (id % 16) * 64; r0 = (id / 16) * 64;
  }
  int r = tid >> 2, cp = (tid & 3) * 16;
  const float4* s4 = reinterpret_cast<const float4*>(W + (size_t)(r0 + r) * C + c0 + cp);
  float4 f0 = s4[0], f1 = s4[1], f2 = s4[2], f3 = s4[3];
  short* tr = &t[r][cp];
  tr[0] = f2bf(f0.x); tr[1] = f2bf(f0.y); tr[2]  = f2bf(f0.z); tr[3]  = f2bf(f0.w);
  tr[4] = f2bf(f1.x); tr[5] = f2bf(f1.y); tr[6]  = f2bf(f1.z); tr[7]  = f2bf(f1.w);
  tr[8] = f2bf(f2.x); tr[9] = f2bf(f2.y); tr[10] = f2bf(f2.z); tr[11] = f2bf(f2.w);
  tr[12] = f2bf(f3.x); tr[13] = f2bf(f3.y); tr[14] = f2bf(f3.z); tr[15] = f2bf(f3.w);
  __syncthreads();
  int cc = tid >> 2, rp = (tid & 3) * 16;
  short buf[16];
#pragma unroll
  for (int i = 0; i < 16; ++i) buf[i] = t[rp + i][cc];
  short* dst = WT + (size_t)(c0 + cc) * R + r0 + rp;
  *reinterpret_cast<s16x8*>(dst) = *reinterpret_cast<s16x8*>(buf);
  *reinterpret_cast<s16x8*>(dst + 8) = *reinterpret_cast<s16x8*>(buf + 8);
}

// ------------- GEMM0: xb[8192][1024] x wqkvT[3072][1024] -> q,k ([B][H][N][64]) + vT ----
// 128x128 tile, BK=32, 4 waves, 2-slot LDS (32KB), LB(256,2). 2-phase pipeline:
// per tile {STAGE(t+1); ds_read(t); MFMA; vmcnt(0); barrier}.
// q pre-scaled by CL_; v written transposed to vT[B][H][64][N]. (R11 measured-best.)
__global__ __launch_bounds__(256, 2)
void k_gemm0(const short* __restrict__ A, const short* __restrict__ BT,
             short* __restrict__ oq, short* __restrict__ ok, short* __restrict__ ovT) {
  __shared__ __align__(16) char smem[32768];  // 2 slots x (A 8KB + B 8KB)
  constexpr int K = 1024, NT = 32;
  const int tid = threadIdx.x;
  const int m0 = blockIdx.x * 128, n0 = blockIdx.y * 128;
  const int lane = tid & 63, w = tid >> 6, g = lane >> 4, c = lane & 15;
  const int wr = w >> 1, wc = w & 1;
  f32x4 acc[4][4] = {};
  const int trow = tid >> 2, tk = (tid & 3) * 8;
  const short* ga = A + (size_t)(m0 + trow) * K + tk;
  const short* gb = BT + (size_t)(n0 + trow) * K + tk;
#define STG0(T)                                                    \
  {                                                                \
    char* nb = smem + ((T) & 1) * 16384;                           \
    gload16(ga + (T) * 32, nb + tid * 16);                         \
    gload16(ga + (size_t)64 * K + (T) * 32, nb + 4096 + tid * 16); \
    gload16(gb + (T) * 32, nb + 8192 + tid * 16);                  \
    gload16(gb + (size_t)64 * K + (T) * 32, nb + 12288 + tid * 16);\
  }
  STG0(0);
  asm volatile("s_waitcnt vmcnt(0)" ::: "memory");
  __builtin_amdgcn_s_barrier();
  for (int t = 0; t < NT; ++t) {
    if (t + 1 < NT) STG0(t + 1);
    const char* sb = smem + (t & 1) * 16384;
    s16x8 af[4], bf[4];
#pragma unroll
    for (int i = 0; i < 4; ++i)
      af[i] = *reinterpret_cast<const s16x8*>(sb + (wr * 64 + i * 16 + c) * 64 + g * 16);
#pragma unroll
    for (int j = 0; j < 4; ++j)
      bf[j] = *reinterpret_cast<const s16x8*>(sb + 8192 + (wc * 64 + j * 16 + c) * 64 + g * 16);
    __builtin_amdgcn_s_setprio(1);
#pragma unroll
    for (int i = 0; i < 4; ++i)
#pragma unroll
      for (int j = 0; j < 4; ++j)
        acc[i][j] = __builtin_amdgcn_mfma_f32_16x16x32_bf16(af[i], bf[j], acc[i][j], 0, 0, 0);
    __builtin_amdgcn_s_setprio(0);
    asm volatile("s_waitcnt vmcnt(0)" ::: "memory");
    __builtin_amdgcn_s_barrier();
  }
#undef STG0
  // epilogue: part 0 -> q (scaled), 1 -> k, 2 -> vT (packed 8B rows along n)
#pragma unroll
  for (int bj = 0; bj < 4; ++bj) {
    int ncol = n0 + wc * 64 + bj * 16 + c;
    int part = ncol >> 10;
    int c10 = ncol & 1023;
    int h = c10 >> 6, d = c10 & 63;
    if (part == 2) {
#pragma unroll
      for (int ai = 0; ai < 4; ++ai) {
        int mrow = m0 + wr * 64 + ai * 16 + g * 4;  // 4 consecutive rows
        int b = mrow >> 11, nr = mrow & 2047;
        uint2 pk;
        pk.x = cvtpk(acc[ai][bj][0], acc[ai][bj][1]);
        pk.y = cvtpk(acc[ai][bj][2], acc[ai][bj][3]);
        *reinterpret_cast<uint2*>(ovT + ((size_t)((b * H_ + h) * 64 + d) * N_ + nr)) = pk;
      }
    } else {
      short* dst0 = (part == 0) ? oq : ok;
      float qs = (part == 0) ? CL_ : 1.0f;
#pragma unroll
      for (int ai = 0; ai < 4; ++ai) {
#pragma unroll
        for (int r = 0; r < 4; ++r) {
          int mrow = m0 + wr * 64 + ai * 16 + g * 4 + r;
          int b = mrow >> 11, nr = mrow & 2047;
          dst0[((size_t)((b * H_ + h) * N_ + nr) << 6) + d] = f2bf(acc[ai][bj][r] * qs);
        }
      }
    }
  }
}

// ------------- GEMM1 (out-proj): 128x128 tile, BK=64, swizzled LDS, 2-phase ----
// Halves barrier/vmcnt(0) drains (32 -> 16 K-steps). 64KB LDS: gemm1 is grid-capped
// at 2 blocks/CU anyway, so no occupancy loss. 128B LDS rows would 16-way conflict:
// both-sides swz8 swizzle (R8-verified pattern) — linear LDS dest, source col ^swz8(row)
// at stage, ^swz8(row) on read. K accumulation order unchanged (t asc, ks asc).
__global__ __launch_bounds__(256, 2)
void k_gemm1(const short* __restrict__ A, const short* __restrict__ BT,
             int M, int N, int K, const float* __restrict__ bias, float* __restrict__ out) {
  __shared__ __align__(16) char smem[65536];  // 2 slots x (A 16KB + B 16KB)
  const int NT = K / 64;  // 16
  const int tid = threadIdx.x;
  const int m0 = blockIdx.x * 128, n0 = blockIdx.y * 128;
  const int lane = tid & 63, w = tid >> 6, g = lane >> 4, c = lane & 15;
  const int wr = w >> 1, wc = w & 1;
  f32x4 acc[4][4] = {};
  // staging: 4 chunks each for A and B. chunk ci -> row ci>>3, LDS pos ci (linear),
  // global source col ((ci&7) ^ swz8(row)) * 8 elements.
  int ci0 = tid, ci1 = tid + 256, ci2 = tid + 512, ci3 = tid + 768;
  int r0_ = ci0 >> 3, r1_ = ci1 >> 3, r2_ = ci2 >> 3, r3_ = ci3 >> 3;
  int sc0 = ((ci0 & 7) ^ ((r0_ ^ (r0_ >> 3)) & 7)) * 8;
  int sc1 = ((ci1 & 7) ^ ((r1_ ^ (r1_ >> 3)) & 7)) * 8;
  int sc2 = ((ci2 & 7) ^ ((r2_ ^ (r2_ >> 3)) & 7)) * 8;
  int sc3 = ((ci3 & 7) ^ ((r3_ ^ (r3_ >> 3)) & 7)) * 8;
  const short* ga0 = A + (size_t)(m0 + r0_) * K + sc0;
  const short* ga1 = A + (size_t)(m0 + r1_) * K + sc1;
  const short* ga2 = A + (size_t)(m0 + r2_) * K + sc2;
  const short* ga3 = A + (size_t)(m0 + r3_) * K + sc3;
  const short* gb0 = BT + (size_t)(n0 + r0_) * K + sc0;
  const short* gb1 = BT + (size_t)(n0 + r1_) * K + sc1;
  const short* gb2 = BT + (size_t)(n0 + r2_) * K + sc2;
  const short* gb3 = BT + (size_t)(n0 + r3_) * K + sc3;
#define STG1(T)                                                      \
  {                                                                  \
    char* nb = smem + ((T) & 1) * 32768;                             \
    gload16(ga0 + (T) * 64, nb + ci0 * 16);                          \
    gload16(ga1 + (T) * 64, nb + ci1 * 16);                          \
    gload16(ga2 + (T) * 64, nb + ci2 * 16);                          \
    gload16(ga3 + (T) * 64, nb + ci3 * 16);                          \
    gload16(gb0 + (T) * 64, nb + 16384 + ci0 * 16);                  \
    gload16(gb1 + (T) * 64, nb + 16384 + ci1 * 16);                  \
    gload16(gb2 + (T) * 64, nb + 16384 + ci2 * 16);                  \
    gload16(gb3 + (T) * 64, nb + 16384 + ci3 * 16);                  \
  }
  // read offsets: row ra -> byte ra*128 + ((ks*4+g)^swz8(ra))*16
  int offA[4][2], offB[4][2];
#pragma unroll
  for (int i = 0; i < 4; ++i) {
    int ra = wr * 64 + i * 16 + c;
    int sa = (ra ^ (ra >> 3)) & 7;
    int rb = wc * 64 + i * 16 + c;
    int sb2 = (rb ^ (rb >> 3)) & 7;
#pragma unroll
    for (int ks = 0; ks < 2; ++ks) {
      offA[i][ks] = ra * 128 + (((ks * 4 + g) ^ sa) * 16);
      offB[i][ks] = 16384 + rb * 128 + (((ks * 4 + g) ^ sb2) * 16);
    }
  }
  STG1(0);
  asm volatile("s_waitcnt vmcnt(0)" ::: "memory");
  __builtin_amdgcn_s_barrier();
  for (int t = 0; t < NT; ++t) {
    if (t + 1 < NT) STG1(t + 1);
    const char* sb = smem + (t & 1) * 32768;
#pragma unroll
    for (int ks = 0; ks < 2; ++ks) {
      s16x8 af[4], bf[4];
#pragma unroll
      for (int i = 0; i < 4; ++i)
        af[i] = *reinterpret_cast<const s16x8*>(sb + offA[i][ks]);
#pragma unroll
      for (int j = 0; j < 4; ++j)
        bf[j] = *reinterpret_cast<const s16x8*>(sb + offB[j][ks]);
      __builtin_amdgcn_s_setprio(1);
#pragma unroll
      for (int i = 0; i < 4; ++i)
#pragma unroll
        for (int j = 0; j < 4; ++j)
          acc[i][j] = __builtin_amdgcn_mfma_f32_16x16x32_bf16(af[i], bf[j], acc[i][j], 0, 0, 0);
      __builtin_amdgcn_s_setprio(0);
    }
    asm volatile("s_waitcnt vmcnt(0)" ::: "memory");
    __builtin_amdgcn_s_barrier();
  }
#undef STG1
#pragma unroll
  for (int bj = 0; bj < 4; ++bj) {
    int ncol = n0 + wc * 64 + bj * 16 + c;
    float bb = bias[ncol];
#pragma unroll
    for (int ai = 0; ai < 4; ++ai) {
#pragma unroll
      for (int r = 0; r < 4; ++r) {
        int mrow = m0 + wr * 64 + ai * 16 + g * 4 + r;
        out[(size_t)mrow * N + ncol] = acc[ai][bj][r] + bb;
      }
    }
  }
}

// ------------- flash attention: 32x32 MFMA, QBLK=32/wave, 4 blocks/CU (unchanged) ------
__global__ __launch_bounds__(256, 4)
void k_attn(const short* __restrict__ q, const short* __restrict__ kk,
            const short* __restrict__ vT, short* __restrict__ ao) {
  __shared__ __align__(16) char smem[32768];  // 2 slots x (K 8K + V 8K)
  constexpr int NT = N_ / 64;  // 32 kv tiles
  int bh = blockIdx.x, qb = blockIdx.y;  // bh fast => same-head blocks on one XCD
  int b = bh >> 4, head = bh & 15;
  int tid = threadIdx.x, w = tid >> 6, lane = tid & 63;
  int half = lane >> 5, qc = lane & 31;
  const size_t ho = (size_t)bh * (N_ * 64);
  const short* Q = q + ho;
  const char* Kc = reinterpret_cast<const char*>(kk + ho);
  const char* Vc = reinterpret_cast<const char*>(vT + ho);
  int q0w = qb * 128 + w * 32;
  s16x8 qf[4];
#pragma unroll
  for (int ks = 0; ks < 4; ++ks)
    qf[ks] = *reinterpret_cast<const s16x8*>(Q + (size_t)(q0w + qc) * 64 + ks * 16 + half * 8);
  f32x16 ot[2] = {};
  float lp0 = 0.f, lp1 = 0.f, lp2 = 0.f, lp3 = 0.f;
  const int rsw0 = ((qc ^ (qc >> 3)) & 7) << 4;
  const int rsw1 = rsw0 ^ 0x40;
  const int s_i0 = tid, s_i1 = tid + 256;
  const int s_r0 = s_i0 >> 3, s_r1 = s_i1 >> 3;
  const int s_c0 = (((s_i0 & 7) ^ ((s_r0 ^ (s_r0 >> 3)) & 7)) << 4);
  const int s_c1 = (((s_i1 & 7) ^ ((s_r1 ^ (s_r1 >> 3)) & 7)) << 4);
#define STAGE(T)                                                                       \
  {                                                                                    \
    char* nb = smem + ((T) & 1) * 16384;                                               \
    gload16(Kc + (size_t)((T) * 64 + s_r0) * 128 + s_c0, nb + s_i0 * 16);              \
    gload16(Kc + (size_t)((T) * 64 + s_r1) * 128 + s_c1, nb + s_i1 * 16);              \
    gload16(Vc + (size_t)s_r0 * 4096 + (T) * 128 + s_c0, nb + 8192 + s_i0 * 16);       \
    gload16(Vc + (size_t)s_r1 * 4096 + (T) * 128 + s_c1, nb + 8192 + s_i1 * 16);       \
  }
  STAGE(0);
  __syncthreads();
  for (int tt = 0; tt < NT; ++tt) {
    if (tt + 1 < NT) STAGE(tt + 1);
    const char* kb_ = smem + (tt & 1) * 16384;
    const char* vb_ = kb_ + 8192;
    f32x16 st[2];
#pragma unroll
    for (int j = 0; j < 2; ++j) {
      const int rs = j ? rsw1 : rsw0;
      s16x8 kfj[4];
#pragma unroll
      for (int ks = 0; ks < 4; ++ks)
        kfj[ks] = *reinterpret_cast<const s16x8*>(kb_ + (j * 32 + qc) * 128 + ((ks * 32 + half * 16) ^ rs));
      f32x16 acc = {};
      __builtin_amdgcn_s_setprio(1);
#pragma unroll
      for (int ks = 0; ks < 4; ++ks)
        acc = __builtin_amdgcn_mfma_f32_32x32x16_bf16(kfj[ks], qf[ks], acc, 0, 0, 0);
      __builtin_amdgcn_s_setprio(0);
      st[j] = acc;
    }
#pragma unroll
    for (int j = 0; j < 2; ++j)
#pragma unroll
      for (int r = 0; r < 16; ++r) {
        float p = __builtin_amdgcn_exp2f(st[j][r]);
        st[j][r] = p;
        if ((r & 3) == 0) lp0 += p;
        else if ((r & 3) == 1) lp1 += p;
        else if ((r & 3) == 2) lp2 += p;
        else lp3 += p;
      }
    u32x4 pwv[4];
#pragma unroll
    for (int j = 0; j < 2; ++j)
#pragma unroll
      for (int bb = 0; bb < 2; ++bb)
#pragma unroll
        for (int p = 0; p < 2; ++p) {
          uint32_t Aw = cvtpk(st[j][8 * bb + 2 * p], st[j][8 * bb + 2 * p + 1]);
          uint32_t Bw = cvtpk(st[j][8 * bb + 4 + 2 * p], st[j][8 * bb + 4 + 2 * p + 1]);
          asm volatile("v_permlane32_swap_b32 %0, %1" : "+v"(Aw), "+v"(Bw));
          pwv[j * 2 + bb][p] = Aw;
          pwv[j * 2 + bb][p + 2] = Bw;
        }
#pragma unroll
    for (int db = 0; db < 2; ++db) {
      const int rs = db ? rsw1 : rsw0;
      s16x8 vf[4];
#pragma unroll
      for (int kb4 = 0; kb4 < 4; ++kb4)
        vf[kb4] = *reinterpret_cast<const s16x8*>(vb_ + (db * 32 + qc) * 128 + ((kb4 * 32 + half * 16) ^ rs));
      f32x16 acc = ot[db];
      __builtin_amdgcn_s_setprio(1);
#pragma unroll
      for (int kb4 = 0; kb4 < 4; ++kb4)
        acc = __builtin_amdgcn_mfma_f32_32x32x16_bf16(
            vf[kb4], __builtin_bit_cast(s16x8, pwv[kb4]), acc, 0, 0, 0);
      __builtin_amdgcn_s_setprio(0);
      ot[db] = acc;
    }
    __syncthreads();
  }
#undef STAGE
  float lp = (lp0 + lp1) + (lp2 + lp3);
  float linv = 1.f / (lp + __shfl_xor(lp, 32, 64));
  short* Oq = reinterpret_cast<short*>(smem) + w * 2304;  // [32][72]
#pragma unroll
  for (int db = 0; db < 2; ++db)
#pragma unroll
    for (int m = 0; m < 4; ++m) {
      uint2 pk;
      pk.x = cvtpk(ot[db][4 * m] * linv, ot[db][4 * m + 1] * linv);
      pk.y = cvtpk(ot[db][4 * m + 2] * linv, ot[db][4 * m + 3] * linv);
      *reinterpret_cast<uint2*>(Oq + qc * 72 + db * 32 + m * 8 + half * 4) = pk;
    }
  int q2 = lane >> 1, dcol = (lane & 1) * 32;
  size_t ro = (size_t)(b * N_ + q0w + q2) * 1024 + head * 64 + dcol;
#pragma unroll
  for (int ch = 0; ch < 4; ++ch) {
    s16x8 vv = *reinterpret_cast<const s16x8*>(Oq + q2 * 72 + dcol + ch * 8);
    *reinterpret_cast<s16x8*>(ao + ro + ch * 8) = vv;
  }
}

extern "C" void kernel_launch(void* const* d_in, const int* in_sizes, int n_in,
                              void* d_out, int out_size, void* d_ws, size_t ws_size,
                              hipStream_t stream) {
  const float* x = (const float*)d_in[0];
  const float* w_qkv = (const float*)d_in[1];
  const float* w_out = (const float*)d_in[2];
  const float* b_out = (const float*)d_in[3];
  float* out = (float*)d_out;
  char* ws = (char*)d_ws;
  short* xb    = (short*)(ws);                // [8192][1024] bf16 (reused as ao later)
  short* wqkvT = (short*)(ws + 16777216);     // [3072][1024]
  short* woutT = (short*)(ws + 23068672);     // [1024][1024]
  short* qB    = (short*)(ws + 25165824);     // [B][H][N][64] (pre-scaled by CL_)
  short* kB    = (short*)(ws + 41943040);
  short* vTT   = (short*)(ws + 75497472);     // [B][H][64][N] (written by gemm0)
  short* ao    = xb;                          // alias: xb dead after gemm0

  k_prep<<<5120, 256, 0, stream>>>(x, xb, w_qkv, wqkvT, w_out, woutT);
  k_gemm0<<<dim3(64, 24), 256, 0, stream>>>(xb, wqkvT, qB, kB, vTT);
  k_attn<<<dim3(64, 16), 256, 0, stream>>>(qB, kB, vTT, ao);
  k_gemm1<<<dim3(64, 8), 256, 0, stream>>>(ao, woutT, 8192, 1024, 1024, b_out, out);
}

// Round 18
// 177.034 us; speedup vs baseline: 1.0968x; 1.0521x over previous
//
#include <hip/hip_runtime.h>
#include <hip/hip_bf16.h>
#include <stdint.h>

typedef __attribute__((ext_vector_type(4))) float f32x4;
typedef __attribute__((ext_vector_type(16))) float f32x16;
typedef __attribute__((ext_vector_type(8))) short s16x8;
typedef __attribute__((ext_vector_type(4))) short s16x4;
typedef __attribute__((ext_vector_type(4))) unsigned int u32x4;

#define DEV static __device__ __forceinline__

constexpr int B_ = 4, H_ = 16, N_ = 2048;
constexpr float CL_ = 0.18033688011112042f;  // dh^-0.5 * log2(e), folded into q

DEV short f2bf(float x) {
  __hip_bfloat16 h = __float2bfloat16(x);
  return *reinterpret_cast<short*>(&h);
}

DEV uint32_t cvtpk(float lo, float hi) {  // packed bf16 (RNE), 1 instr
  uint32_t r;
  asm("v_cvt_pk_bf16_f32 %0, %1, %2" : "=v"(r) : "v"(lo), "v"(hi));
  return r;
}

DEV void gload16(const void* g, void* l) {
  __builtin_amdgcn_global_load_lds((const __attribute__((address_space(1))) void*)g,
                                   (__attribute__((address_space(3))) void*)l, 16, 0, 0);
}

// ---------------- fused prep: x cast + both weight transposes (one launch) ----------
__global__ void k_prep(const float* __restrict__ x, short* __restrict__ xb,
                       const float* __restrict__ wqkv, short* __restrict__ wqkvT,
                       const float* __restrict__ wout, short* __restrict__ woutT) {
  __shared__ short t[64][72];
  int bid = blockIdx.x, tid = threadIdx.x;
  if (bid < 4096) {
    int i = (bid * 256 + tid) * 8;
    const float4* p = reinterpret_cast<const float4*>(x + i);
    float4 a = p[0], b = p[1];
    s16x8 o;
    o[0] = f2bf(a.x); o[1] = f2bf(a.y); o[2] = f2bf(a.z); o[3] = f2bf(a.w);
    o[4] = f2bf(b.x); o[5] = f2bf(b.y); o[6] = f2bf(b.z); o[7] = f2bf(b.w);
    *reinterpret_cast<s16x8*>(xb + i) = o;
    return;
  }
  const float* W;
  short* WT;
  int R = 1024, C, r0, c0;
  if (bid < 4864) {
    int id = bid - 4096;
    W = wqkv; WT = wqkvT; C = 3072;
    c0 = (id % 48) * 64; r0 = (id / 48) * 64;
  } else {
    int id = bid - 4864;
    W = wout; WT = woutT; C = 1024;
    c0 = (id % 16) * 64; r0 = (id / 16) * 64;
  }
  int r = tid >> 2, cp = (tid & 3) * 16;
  const float4* s4 = reinterpret_cast<const float4*>(W + (size_t)(r0 + r) * C + c0 + cp);
  float4 f0 = s4[0], f1 = s4[1], f2 = s4[2], f3 = s4[3];
  short* tr = &t[r][cp];
  tr[0] = f2bf(f0.x); tr[1] = f2bf(f0.y); tr[2]  = f2bf(f0.z); tr[3]  = f2bf(f0.w);
  tr[4] = f2bf(f1.x); tr[5] = f2bf(f1.y); tr[6]  = f2bf(f1.z); tr[7]  = f2bf(f1.w);
  tr[8] = f2bf(f2.x); tr[9] = f2bf(f2.y); tr[10] = f2bf(f2.z); tr[11] = f2bf(f2.w);
  tr[12] = f2bf(f3.x); tr[13] = f2bf(f3.y); tr[14] = f2bf(f3.z); tr[15] = f2bf(f3.w);
  __syncthreads();
  int cc = tid >> 2, rp = (tid & 3) * 16;
  short buf[16];
#pragma unroll
  for (int i = 0; i < 16; ++i) buf[i] = t[rp + i][cc];
  short* dst = WT + (size_t)(c0 + cc) * R + r0 + rp;
  *reinterpret_cast<s16x8*>(dst) = *reinterpret_cast<s16x8*>(buf);
  *reinterpret_cast<s16x8*>(dst + 8) = *reinterpret_cast<s16x8*>(buf + 8);
}

// ------------- GEMM0: xb[8192][1024] x wqkvT[3072][1024] -> q,k ([B][H][N][64]) + vT ----
// 128x128 tile, BK=64 (R18: halves barrier drains 32->16), 4 waves, 2-slot 64KB LDS
// (still 2 blocks/CU at LB(256,2)), both-sides swz8 swizzle (R17-verified pattern).
// 2-phase: {STAGE(t+1); ds_read(t); MFMA ks=0,1; vmcnt(0); barrier}.
// q pre-scaled by CL_; v written transposed to vT[B][H][64][N].
__global__ __launch_bounds__(256, 2)
void k_gemm0(const short* __restrict__ A, const short* __restrict__ BT,
             short* __restrict__ oq, short* __restrict__ ok, short* __restrict__ ovT) {
  __shared__ __align__(16) char smem[65536];  // 2 slots x (A 16KB + B 16KB)
  constexpr int K = 1024, NT = 16;
  const int tid = threadIdx.x;
  const int m0 = blockIdx.x * 128, n0 = blockIdx.y * 128;
  const int lane = tid & 63, w = tid >> 6, g = lane >> 4, c = lane & 15;
  const int wr = w >> 1, wc = w & 1;
  f32x4 acc[4][4] = {};
  // staging: 4 chunks each for A and B; chunk ci -> row ci>>3, linear LDS pos ci,
  // global source col ((ci&7) ^ swz8(row)) * 8 elements.
  int ci0 = tid, ci1 = tid + 256, ci2 = tid + 512, ci3 = tid + 768;
  int r0_ = ci0 >> 3, r1_ = ci1 >> 3, r2_ = ci2 >> 3, r3_ = ci3 >> 3;
  int sc0 = ((ci0 & 7) ^ ((r0_ ^ (r0_ >> 3)) & 7)) * 8;
  int sc1 = ((ci1 & 7) ^ ((r1_ ^ (r1_ >> 3)) & 7)) * 8;
  int sc2 = ((ci2 & 7) ^ ((r2_ ^ (r2_ >> 3)) & 7)) * 8;
  int sc3 = ((ci3 & 7) ^ ((r3_ ^ (r3_ >> 3)) & 7)) * 8;
  const short* ga0 = A + (size_t)(m0 + r0_) * K + sc0;
  const short* ga1 = A + (size_t)(m0 + r1_) * K + sc1;
  const short* ga2 = A + (size_t)(m0 + r2_) * K + sc2;
  const short* ga3 = A + (size_t)(m0 + r3_) * K + sc3;
  const short* gb0 = BT + (size_t)(n0 + r0_) * K + sc0;
  const short* gb1 = BT + (size_t)(n0 + r1_) * K + sc1;
  const short* gb2 = BT + (size_t)(n0 + r2_) * K + sc2;
  const short* gb3 = BT + (size_t)(n0 + r3_) * K + sc3;
#define STG0(T)                                                      \
  {                                                                  \
    char* nb = smem + ((T) & 1) * 32768;                             \
    gload16(ga0 + (T) * 64, nb + ci0 * 16);                          \
    gload16(ga1 + (T) * 64, nb + ci1 * 16);                          \
    gload16(ga2 + (T) * 64, nb + ci2 * 16);                          \
    gload16(ga3 + (T) * 64, nb + ci3 * 16);                          \
    gload16(gb0 + (T) * 64, nb + 16384 + ci0 * 16);                  \
    gload16(gb1 + (T) * 64, nb + 16384 + ci1 * 16);                  \
    gload16(gb2 + (T) * 64, nb + 16384 + ci2 * 16);                  \
    gload16(gb3 + (T) * 64, nb + 16384 + ci3 * 16);                  \
  }
  // read offsets: row ra -> byte ra*128 + ((ks*4+g)^swz8(ra))*16
  int offA[4][2], offB[4][2];
#pragma unroll
  for (int i = 0; i < 4; ++i) {
    int ra = wr * 64 + i * 16 + c;
    int sa = (ra ^ (ra >> 3)) & 7;
    int rb = wc * 64 + i * 16 + c;
    int sb2 = (rb ^ (rb >> 3)) & 7;
#pragma unroll
    for (int ks = 0; ks < 2; ++ks) {
      offA[i][ks] = ra * 128 + (((ks * 4 + g) ^ sa) * 16);
      offB[i][ks] = 16384 + rb * 128 + (((ks * 4 + g) ^ sb2) * 16);
    }
  }
  STG0(0);
  asm volatile("s_waitcnt vmcnt(0)" ::: "memory");
  __builtin_amdgcn_s_barrier();
  for (int t = 0; t < NT; ++t) {
    if (t + 1 < NT) STG0(t + 1);
    const char* sb = smem + (t & 1) * 32768;
#pragma unroll
    for (int ks = 0; ks < 2; ++ks) {
      s16x8 af[4], bf[4];
#pragma unroll
      for (int i = 0; i < 4; ++i)
        af[i] = *reinterpret_cast<const s16x8*>(sb + offA[i][ks]);
#pragma unroll
      for (int j = 0; j < 4; ++j)
        bf[j] = *reinterpret_cast<const s16x8*>(sb + offB[j][ks]);
      __builtin_amdgcn_s_setprio(1);
#pragma unroll
      for (int i = 0; i < 4; ++i)
#pragma unroll
        for (int j = 0; j < 4; ++j)
          acc[i][j] = __builtin_amdgcn_mfma_f32_16x16x32_bf16(af[i], bf[j], acc[i][j], 0, 0, 0);
      __builtin_amdgcn_s_setprio(0);
    }
    asm volatile("s_waitcnt vmcnt(0)" ::: "memory");
    __builtin_amdgcn_s_barrier();
  }
#undef STG0
  // epilogue: part 0 -> q (scaled), 1 -> k, 2 -> vT (packed 8B rows along n)
#pragma unroll
  for (int bj = 0; bj < 4; ++bj) {
    int ncol = n0 + wc * 64 + bj * 16 + c;
    int part = ncol >> 10;
    int c10 = ncol & 1023;
    int h = c10 >> 6, d = c10 & 63;
    if (part == 2) {
#pragma unroll
      for (int ai = 0; ai < 4; ++ai) {
        int mrow = m0 + wr * 64 + ai * 16 + g * 4;  // 4 consecutive rows
        int b = mrow >> 11, nr = mrow & 2047;
        uint2 pk;
        pk.x = cvtpk(acc[ai][bj][0], acc[ai][bj][1]);
        pk.y = cvtpk(acc[ai][bj][2], acc[ai][bj][3]);
        *reinterpret_cast<uint2*>(ovT + ((size_t)((b * H_ + h) * 64 + d) * N_ + nr)) = pk;
      }
    } else {
      short* dst0 = (part == 0) ? oq : ok;
      float qs = (part == 0) ? CL_ : 1.0f;
#pragma unroll
      for (int ai = 0; ai < 4; ++ai) {
#pragma unroll
        for (int r = 0; r < 4; ++r) {
          int mrow = m0 + wr * 64 + ai * 16 + g * 4 + r;
          int b = mrow >> 11, nr = mrow & 2047;
          dst0[((size_t)((b * H_ + h) * N_ + nr) << 6) + d] = f2bf(acc[ai][bj][r] * qs);
        }
      }
    }
  }
}

// ------------- GEMM1 (out-proj): 128x128 tile, BK=64, swizzled LDS, 2-phase (R17) ----
__global__ __launch_bounds__(256, 2)
void k_gemm1(const short* __restrict__ A, const short* __restrict__ BT,
             int M, int N, int K, const float* __restrict__ bias, float* __restrict__ out) {
  __shared__ __align__(16) char smem[65536];  // 2 slots x (A 16KB + B 16KB)
  const int NT = K / 64;  // 16
  const int tid = threadIdx.x;
  const int m0 = blockIdx.x * 128, n0 = blockIdx.y * 128;
  const int lane = tid & 63, w = tid >> 6, g = lane >> 4, c = lane & 15;
  const int wr = w >> 1, wc = w & 1;
  f32x4 acc[4][4] = {};
  int ci0 = tid, ci1 = tid + 256, ci2 = tid + 512, ci3 = tid + 768;
  int r0_ = ci0 >> 3, r1_ = ci1 >> 3, r2_ = ci2 >> 3, r3_ = ci3 >> 3;
  int sc0 = ((ci0 & 7) ^ ((r0_ ^ (r0_ >> 3)) & 7)) * 8;
  int sc1 = ((ci1 & 7) ^ ((r1_ ^ (r1_ >> 3)) & 7)) * 8;
  int sc2 = ((ci2 & 7) ^ ((r2_ ^ (r2_ >> 3)) & 7)) * 8;
  int sc3 = ((ci3 & 7) ^ ((r3_ ^ (r3_ >> 3)) & 7)) * 8;
  const short* ga0 = A + (size_t)(m0 + r0_) * K + sc0;
  const short* ga1 = A + (size_t)(m0 + r1_) * K + sc1;
  const short* ga2 = A + (size_t)(m0 + r2_) * K + sc2;
  const short* ga3 = A + (size_t)(m0 + r3_) * K + sc3;
  const short* gb0 = BT + (size_t)(n0 + r0_) * K + sc0;
  const short* gb1 = BT + (size_t)(n0 + r1_) * K + sc1;
  const short* gb2 = BT + (size_t)(n0 + r2_) * K + sc2;
  const short* gb3 = BT + (size_t)(n0 + r3_) * K + sc3;
#define STG1(T)                                                      \
  {                                                                  \
    char* nb = smem + ((T) & 1) * 32768;                             \
    gload16(ga0 + (T) * 64, nb + ci0 * 16);                          \
    gload16(ga1 + (T) * 64, nb + ci1 * 16);                          \
    gload16(ga2 + (T) * 64, nb + ci2 * 16);                          \
    gload16(ga3 + (T) * 64, nb + ci3 * 16);                          \
    gload16(gb0 + (T) * 64, nb + 16384 + ci0 * 16);                  \
    gload16(gb1 + (T) * 64, nb + 16384 + ci1 * 16);                  \
    gload16(gb2 + (T) * 64, nb + 16384 + ci2 * 16);                  \
    gload16(gb3 + (T) * 64, nb + 16384 + ci3 * 16);                  \
  }
  int offA[4][2], offB[4][2];
#pragma unroll
  for (int i = 0; i < 4; ++i) {
    int ra = wr * 64 + i * 16 + c;
    int sa = (ra ^ (ra >> 3)) & 7;
    int rb = wc * 64 + i * 16 + c;
    int sb2 = (rb ^ (rb >> 3)) & 7;
#pragma unroll
    for (int ks = 0; ks < 2; ++ks) {
      offA[i][ks] = ra * 128 + (((ks * 4 + g) ^ sa) * 16);
      offB[i][ks] = 16384 + rb * 128 + (((ks * 4 + g) ^ sb2) * 16);
    }
  }
  STG1(0);
  asm volatile("s_waitcnt vmcnt(0)" ::: "memory");
  __builtin_amdgcn_s_barrier();
  for (int t = 0; t < NT; ++t) {
    if (t + 1 < NT) STG1(t + 1);
    const char* sb = smem + (t & 1) * 32768;
#pragma unroll
    for (int ks = 0; ks < 2; ++ks) {
      s16x8 af[4], bf[4];
#pragma unroll
      for (int i = 0; i < 4; ++i)
        af[i] = *reinterpret_cast<const s16x8*>(sb + offA[i][ks]);
#pragma unroll
      for (int j = 0; j < 4; ++j)
        bf[j] = *reinterpret_cast<const s16x8*>(sb + offB[j][ks]);
      __builtin_amdgcn_s_setprio(1);
#pragma unroll
      for (int i = 0; i < 4; ++i)
#pragma unroll
        for (int j = 0; j < 4; ++j)
          acc[i][j] = __builtin_amdgcn_mfma_f32_16x16x32_bf16(af[i], bf[j], acc[i][j], 0, 0, 0);
      __builtin_amdgcn_s_setprio(0);
    }
    asm volatile("s_waitcnt vmcnt(0)" ::: "memory");
    __builtin_amdgcn_s_barrier();
  }
#undef STG1
#pragma unroll
  for (int bj = 0; bj < 4; ++bj) {
    int ncol = n0 + wc * 64 + bj * 16 + c;
    float bb = bias[ncol];
#pragma unroll
    for (int ai = 0; ai < 4; ++ai) {
#pragma unroll
      for (int r = 0; r < 4; ++r) {
        int mrow = m0 + wr * 64 + ai * 16 + g * 4 + r;
        out[(size_t)mrow * N + ncol] = acc[ai][bj][r] + bb;
      }
    }
  }
}

// ------------- flash attention: 32x32 MFMA, QBLK=32/wave, 4 blocks/CU (unchanged) ------
__global__ __launch_bounds__(256, 4)
void k_attn(const short* __restrict__ q, const short* __restrict__ kk,
            const short* __restrict__ vT, short* __restrict__ ao) {
  __shared__ __align__(16) char smem[32768];  // 2 slots x (K 8K + V 8K)
  constexpr int NT = N_ / 64;  // 32 kv tiles
  int bh = blockIdx.x, qb = blockIdx.y;  // bh fast => same-head blocks on one XCD
  int b = bh >> 4, head = bh & 15;
  int tid = threadIdx.x, w = tid >> 6, lane = tid & 63;
  int half = lane >> 5, qc = lane & 31;
  const size_t ho = (size_t)bh * (N_ * 64);
  const short* Q = q + ho;
  const char* Kc = reinterpret_cast<const char*>(kk + ho);
  const char* Vc = reinterpret_cast<const char*>(vT + ho);
  int q0w = qb * 128 + w * 32;
  s16x8 qf[4];
#pragma unroll
  for (int ks = 0; ks < 4; ++ks)
    qf[ks] = *reinterpret_cast<const s16x8*>(Q + (size_t)(q0w + qc) * 64 + ks * 16 + half * 8);
  f32x16 ot[2] = {};
  float lp0 = 0.f, lp1 = 0.f, lp2 = 0.f, lp3 = 0.f;
  const int rsw0 = ((qc ^ (qc >> 3)) & 7) << 4;
  const int rsw1 = rsw0 ^ 0x40;
  const int s_i0 = tid, s_i1 = tid + 256;
  const int s_r0 = s_i0 >> 3, s_r1 = s_i1 >> 3;
  const int s_c0 = (((s_i0 & 7) ^ ((s_r0 ^ (s_r0 >> 3)) & 7)) << 4);
  const int s_c1 = (((s_i1 & 7) ^ ((s_r1 ^ (s_r1 >> 3)) & 7)) << 4);
#define STAGE(T)                                                                       \
  {                                                                                    \
    char* nb = smem + ((T) & 1) * 16384;                                               \
    gload16(Kc + (size_t)((T) * 64 + s_r0) * 128 + s_c0, nb + s_i0 * 16);              \
    gload16(Kc + (size_t)((T) * 64 + s_r1) * 128 + s_c1, nb + s_i1 * 16);              \
    gload16(Vc + (size_t)s_r0 * 4096 + (T) * 128 + s_c0, nb + 8192 + s_i0 * 16);       \
    gload16(Vc + (size_t)s_r1 * 4096 + (T) * 128 + s_c1, nb + 8192 + s_i1 * 16);       \
  }
  STAGE(0);
  __syncthreads();
  for (int tt = 0; tt < NT; ++tt) {
    if (tt + 1 < NT) STAGE(tt + 1);
    const char* kb_ = smem + (tt & 1) * 16384;
    const char* vb_ = kb_ + 8192;
    f32x16 st[2];
#pragma unroll
    for (int j = 0; j < 2; ++j) {
      const int rs = j ? rsw1 : rsw0;
      s16x8 kfj[4];
#pragma unroll
      for (int ks = 0; ks < 4; ++ks)
        kfj[ks] = *reinterpret_cast<const s16x8*>(kb_ + (j * 32 + qc) * 128 + ((ks * 32 + half * 16) ^ rs));
      f32x16 acc = {};
      __builtin_amdgcn_s_setprio(1);
#pragma unroll
      for (int ks = 0; ks < 4; ++ks)
        acc = __builtin_amdgcn_mfma_f32_32x32x16_bf16(kfj[ks], qf[ks], acc, 0, 0, 0);
      __builtin_amdgcn_s_setprio(0);
      st[j] = acc;
    }
#pragma unroll
    for (int j = 0; j < 2; ++j)
#pragma unroll
      for (int r = 0; r < 16; ++r) {
        float p = __builtin_amdgcn_exp2f(st[j][r]);
        st[j][r] = p;
        if ((r & 3) == 0) lp0 += p;
        else if ((r & 3) == 1) lp1 += p;
        else if ((r & 3) == 2) lp2 += p;
        else lp3 += p;
      }
    u32x4 pwv[4];
#pragma unroll
    for (int j = 0; j < 2; ++j)
#pragma unroll
      for (int bb = 0; bb < 2; ++bb)
#pragma unroll
        for (int p = 0; p < 2; ++p) {
          uint32_t Aw = cvtpk(st[j][8 * bb + 2 * p], st[j][8 * bb + 2 * p + 1]);
          uint32_t Bw = cvtpk(st[j][8 * bb + 4 + 2 * p], st[j][8 * bb + 4 + 2 * p + 1]);
          asm volatile("v_permlane32_swap_b32 %0, %1" : "+v"(Aw), "+v"(Bw));
          pwv[j * 2 + bb][p] = Aw;
          pwv[j * 2 + bb][p + 2] = Bw;
        }
#pragma unroll
    for (int db = 0; db < 2; ++db) {
      const int rs = db ? rsw1 : rsw0;
      s16x8 vf[4];
#pragma unroll
      for (int kb4 = 0; kb4 < 4; ++kb4)
        vf[kb4] = *reinterpret_cast<const s16x8*>(vb_ + (db * 32 + qc) * 128 + ((kb4 * 32 + half * 16) ^ rs));
      f32x16 acc = ot[db];
      __builtin_amdgcn_s_setprio(1);
#pragma unroll
      for (int kb4 = 0; kb4 < 4; ++kb4)
        acc = __builtin_amdgcn_mfma_f32_32x32x16_bf16(
            vf[kb4], __builtin_bit_cast(s16x8, pwv[kb4]), acc, 0, 0, 0);
      __builtin_amdgcn_s_setprio(0);
      ot[db] = acc;
    }
    __syncthreads();
  }
#undef STAGE
  float lp = (lp0 + lp1) + (lp2 + lp3);
  float linv = 1.f / (lp + __shfl_xor(lp, 32, 64));
  short* Oq = reinterpret_cast<short*>(smem) + w * 2304;  // [32][72]
#pragma unroll
  for (int db = 0; db < 2; ++db)
#pragma unroll
    for (int m = 0; m < 4; ++m) {
      uint2 pk;
      pk.x = cvtpk(ot[db][4 * m] * linv, ot[db][4 * m + 1] * linv);
      pk.y = cvtpk(ot[db][4 * m + 2] * linv, ot[db][4 * m + 3] * linv);
      *reinterpret_cast<uint2*>(Oq + qc * 72 + db * 32 + m * 8 + half * 4) = pk;
    }
  int q2 = lane >> 1, dcol = (lane & 1) * 32;
  size_t ro = (size_t)(b * N_ + q0w + q2) * 1024 + head * 64 + dcol;
#pragma unroll
  for (int ch = 0; ch < 4; ++ch) {
    s16x8 vv = *reinterpret_cast<const s16x8*>(Oq + q2 * 72 + dcol + ch * 8);
    *reinterpret_cast<s16x8*>(ao + ro + ch * 8) = vv;
  }
}

extern "C" void kernel_launch(void* const* d_in, const int* in_sizes, int n_in,
                              void* d_out, int out_size, void* d_ws, size_t ws_size,
                              hipStream_t stream) {
  const float* x = (const float*)d_in[0];
  const float* w_qkv = (const float*)d_in[1];
  const float* w_out = (const float*)d_in[2];
  const float* b_out = (const float*)d_in[3];
  float* out = (float*)d_out;
  char* ws = (char*)d_ws;
  short* xb    = (short*)(ws);                // [8192][1024] bf16 (reused as ao later)
  short* wqkvT = (short*)(ws + 16777216);     // [3072][1024]
  short* woutT = (short*)(ws + 23068672);     // [1024][1024]
  short* qB    = (short*)(ws + 25165824);     // [B][H][N][64] (pre-scaled by CL_)
  short* kB    = (short*)(ws + 41943040);
  short* vTT   = (short*)(ws + 75497472);     // [B][H][64][N] (written by gemm0)
  short* ao    = xb;                          // alias: xb dead after gemm0

  k_prep<<<5120, 256, 0, stream>>>(x, xb, w_qkv, wqkvT, w_out, woutT);
  k_gemm0<<<dim3(64, 24), 256, 0, stream>>>(xb, wqkvT, qB, kB, vTT);
  k_attn<<<dim3(64, 16), 256, 0, stream>>>(qB, kB, vTT, ao);
  k_gemm1<<<dim3(64, 8), 256, 0, stream>>>(ao, woutT, 8192, 1024, 1024, b_out, out);
}